// Round 4
// baseline (1591.257 us; speedup 1.0000x reference)
//
#include <hip/hip_runtime.h>

typedef __attribute__((ext_vector_type(8))) short bf16x8;
typedef __attribute__((ext_vector_type(4))) float f32x4;

// LDS map (80 KiB total -> 2 blocks/CU):
//  SLICE 0..16K   : dw-conv slice [n 64][ci_local 128] bf16, slot-swizzled; later per-wave P-buf (8 x 2KB)
//  Q     16K..48K : transient v-bounce (8 x 4KB), then q [n 64][c 256] bf16 swizzled
//  K     48K..80K : dw weights (transposed) + biases, then k [m 64][c 256], then attn-out [n 64][c 256]
#define SLICE_B 0
#define Q_B     16384
#define K_B     49152
#define DWB_OFF 27648

__device__ __forceinline__ unsigned short f2b(float f) {
  unsigned int v = __builtin_bit_cast(unsigned int, f);
  v += 0x7FFFu + ((v >> 16) & 1u);
  return (unsigned short)(v >> 16);
}
__device__ __forceinline__ unsigned int pk2(float a, float b) {
  return (unsigned int)f2b(a) | ((unsigned int)f2b(b) << 16);
}
__device__ __forceinline__ bf16x8 pack8(const float4& a, const float4& b) {
  union { unsigned int u[4]; bf16x8 v; } x;
  x.u[0] = pk2(a.x, a.y); x.u[1] = pk2(a.z, a.w);
  x.u[2] = pk2(b.x, b.y); x.u[3] = pk2(b.z, b.w);
  return x.v;
}

__global__ __launch_bounds__(512, 4) void winattn_kernel(
    const float* __restrict__ xg,
    const float* __restrict__ dww0, const float* __restrict__ dwb0,
    const float* __restrict__ pww0, const float* __restrict__ pwb0,
    const float* __restrict__ dww1, const float* __restrict__ dwb1,
    const float* __restrict__ pww1, const float* __restrict__ pwb1,
    const float* __restrict__ dww2, const float* __restrict__ dwb2,
    const float* __restrict__ pww2, const float* __restrict__ pwb2,
    const float* __restrict__ bt,
    const float* __restrict__ pjw, const float* __restrict__ pjb,
    const int* __restrict__ rel,
    float* __restrict__ outg)
{
  __shared__ __align__(16) unsigned char smem[81920];

  const int tid  = threadIdx.x;
  const int lane = tid & 63;
  const int wv   = tid >> 6;        // wave id = head id
  const int lc   = lane & 15;
  const int lq2  = lane >> 4;       // 0..3
  const int b    = blockIdx.x;
  const float* xb = xg + (size_t)b * 16384;

  const float* dwwA[3] = {dww0, dww1, dww2};
  const float* dwbA[3] = {dwb0, dwb1, dwb2};
  const float* pwwA[3] = {pww0, pww1, pww2};
  const float* pwbA[3] = {pwb0, pwb1, pwb2};

  const f32x4 zero4 = {0.f, 0.f, 0.f, 0.f};

  // ---- stage depthwise weights transposed [p][tap][c] + biases into K region ----
  for (int idx = tid; idx < 6912; idx += 512) {
    const int p = idx / 2304, rem = idx % 2304;
    const int c = rem / 9, tap = rem % 9;
    *(float*)(smem + K_B + (((p * 9 + tap) * 256) + c) * 4) = dwwA[p][c * 9 + tap];
  }
  for (int idx = tid; idx < 768; idx += 512) {
    const int p = idx >> 8, c = idx & 255;
    *(float*)(smem + K_B + DWB_OFF + (p * 256 + c) * 4) = dwbA[p][c];
  }
  __syncthreads();

  // ---- depthwise 3x3 + bias + relu for one 128-ch slice, x read from global (f32) ----
  auto dwconv = [&](int p, int s) {
    const int c8 = tid & 15;          // 8-ch slot within slice
    const int strip = tid >> 4;       // 0..31: 2 consecutive w-tokens
    const int l = strip >> 2, w0 = (strip & 3) * 2;
    const int n0 = l * 8 + w0;
#pragma unroll
    for (int h4 = 0; h4 < 2; ++h4) {
      const int cb = s * 128 + c8 * 8 + h4 * 4;   // global channel base (4 ch)
      f32x4 o0 = *(const f32x4*)(smem + K_B + DWB_OFF + (p * 256 + cb) * 4);
      f32x4 o1 = o0;
#pragma unroll
      for (int dl = 0; dl < 3; ++dl) {
        const int row = l + dl - 1;
        const bool rok = (row >= 0) && (row < 8);
        f32x4 xv[4];
#pragma unroll
        for (int wn = 0; wn < 4; ++wn) {
          const int col = w0 + wn - 1;
          f32x4 z = zero4;
          if (rok && col >= 0 && col < 8)
            z = *(const f32x4*)(xb + (row * 8 + col) * 256 + cb);
          xv[wn] = z;
        }
#pragma unroll
        for (int dc = 0; dc < 3; ++dc) {
          const f32x4 wt = *(const f32x4*)(smem + K_B + (((p * 9 + dl * 3 + dc) * 256) + cb) * 4);
#pragma unroll
          for (int j = 0; j < 4; ++j) {
            o0[j] = fmaf(wt[j], xv[dc][j], o0[j]);
            o1[j] = fmaf(wt[j], xv[dc + 1][j], o1[j]);
          }
        }
      }
#pragma unroll
      for (int j = 0; j < 4; ++j) { o0[j] = fmaxf(o0[j], 0.f); o1[j] = fmaxf(o1[j], 0.f); }
      uint2 u0; u0.x = pk2(o0[0], o0[1]); u0.y = pk2(o0[2], o0[3]);
      uint2 u1; u1.x = pk2(o1[0], o1[1]); u1.y = pk2(o1[2], o1[3]);
      const int n1 = n0 + 1;
      *(uint2*)(smem + SLICE_B + n0 * 256 + ((c8 ^ (n0 & 15)) & 15) * 16 + h4 * 8) = u0;
      *(uint2*)(smem + SLICE_B + n1 * 256 + ((c8 ^ (n1 & 15)) & 15) * 16 + h4 * 8) = u1;
    }
  };

  // =============== phase V (branch 2): pw normal orientation, v -> registers ===============
  bf16x8 vfrag[2][2];
  {
    f32x4 av[4][2];
#pragma unroll
    for (int i = 0; i < 4; ++i)
#pragma unroll
      for (int t = 0; t < 2; ++t) av[i][t] = zero4;

    for (int s = 0; s < 2; ++s) {
      dwconv(2, s);
      __syncthreads();
      const float* W = pwwA[2];
#pragma unroll
      for (int kk = 0; kk < 4; ++kk) {
        bf16x8 afr[4];
#pragma unroll
        for (int i = 0; i < 4; ++i) {
          const int m = 16 * i + lc;
          const int s8 = 4 * kk + lq2;
          afr[i] = *(const bf16x8*)(smem + SLICE_B + m * 256 + ((s8 ^ (m & 15)) & 15) * 16);
        }
        bf16x8 bb[2];
#pragma unroll
        for (int t = 0; t < 2; ++t) {
          const int co = 16 * (2 * wv + t) + lc;
          const int ci0 = s * 128 + 32 * kk + 8 * lq2;
          const float4 wa = *(const float4*)(W + co * 256 + ci0);
          const float4 wb = *(const float4*)(W + co * 256 + ci0 + 4);
          bb[t] = pack8(wa, wb);
        }
#pragma unroll
        for (int i = 0; i < 4; ++i)
#pragma unroll
          for (int t = 0; t < 2; ++t)
            av[i][t] = __builtin_amdgcn_mfma_f32_16x16x32_bf16(afr[i], bb[t], av[i][t], 0, 0, 0);
      }
      __syncthreads();
    }
    // epilogue: +bias, bounce v^T into per-wave Q-region scratch, read back as PV A-frags
#pragma unroll
    for (int t = 0; t < 2; ++t) {
      const float pb = pwbA[2][16 * (2 * wv + t) + lc];
      const int c_local = 16 * t + lc;
#pragma unroll
      for (int i = 0; i < 4; ++i) {
        const int m0 = 16 * i + 4 * lq2;
        const float v0 = av[i][t][0] + pb, v1 = av[i][t][1] + pb;
        const float v2 = av[i][t][2] + pb, v3 = av[i][t][3] + pb;
        uint2 u; u.x = pk2(v0, v1); u.y = pk2(v2, v3);
        *(uint2*)(smem + Q_B + wv * 4096 + c_local * 128 +
                  (((m0 >> 3) ^ (c_local & 7)) & 7) * 16 + (lq2 & 1) * 8) = u;
      }
    }
#pragma unroll
    for (int ct = 0; ct < 2; ++ct)
#pragma unroll
      for (int kk = 0; kk < 2; ++kk) {
        const int c_local = 16 * ct + lc;
        const int s8 = 4 * kk + lq2;
        vfrag[ct][kk] = *(const bf16x8*)(smem + Q_B + wv * 4096 + c_local * 128 +
                                         ((s8 ^ (c_local & 7)) & 7) * 16);
      }
  }

  // =============== phases Q (branch 0) and K (branch 1): transposed pw ===============
  for (int qk = 0; qk < 2; ++qk) {
    const int dstB = qk ? K_B : Q_B;
    f32x4 acc[2][4];
#pragma unroll
    for (int cot = 0; cot < 2; ++cot)
#pragma unroll
      for (int nt = 0; nt < 4; ++nt) acc[cot][nt] = zero4;

    for (int s = 0; s < 2; ++s) {
      dwconv(qk, s);
      __syncthreads();
      const float* W = pwwA[qk];
#pragma unroll
      for (int kk = 0; kk < 4; ++kk) {
        bf16x8 afrW[2];
#pragma unroll
        for (int cot = 0; cot < 2; ++cot) {
          const int co = 32 * wv + 16 * cot + lc;
          const int ci0 = s * 128 + 32 * kk + 8 * lq2;
          const float4 wa = *(const float4*)(W + co * 256 + ci0);
          const float4 wb = *(const float4*)(W + co * 256 + ci0 + 4);
          afrW[cot] = pack8(wa, wb);
        }
        bf16x8 bfr[4];
#pragma unroll
        for (int nt = 0; nt < 4; ++nt) {
          const int n = 16 * nt + lc;
          const int s8 = 4 * kk + lq2;
          bfr[nt] = *(const bf16x8*)(smem + SLICE_B + n * 256 + ((s8 ^ (n & 15)) & 15) * 16);
        }
#pragma unroll
        for (int cot = 0; cot < 2; ++cot)
#pragma unroll
          for (int nt = 0; nt < 4; ++nt)
            acc[cot][nt] = __builtin_amdgcn_mfma_f32_16x16x32_bf16(afrW[cot], bfr[nt], acc[cot][nt], 0, 0, 0);
      }
      __syncthreads();
    }
    // epilogue: +bias, b64 stores into [n][c] swizzled region
#pragma unroll
    for (int cot = 0; cot < 2; ++cot) {
      const int c0 = 32 * wv + 16 * cot + 4 * lq2;
      float pb[4];
#pragma unroll
      for (int r = 0; r < 4; ++r) pb[r] = pwbA[qk][c0 + r];
#pragma unroll
      for (int nt = 0; nt < 4; ++nt) {
        const int n = 16 * nt + lc;
        const float v0 = acc[cot][nt][0] + pb[0], v1 = acc[cot][nt][1] + pb[1];
        const float v2 = acc[cot][nt][2] + pb[2], v3 = acc[cot][nt][3] + pb[3];
        uint2 u; u.x = pk2(v0, v1); u.y = pk2(v2, v3);
        *(uint2*)(smem + dstB + n * 512 + (((c0 >> 3) ^ (n & 31)) & 31) * 16 + (lq2 & 1) * 8) = u;
      }
    }
  }

  // =============== attention (no internal barriers; all wave-local) ===============
  {
    const int h = wv;
    bf16x8 kfrag[4];
#pragma unroll
    for (int mt = 0; mt < 4; ++mt) {
      const int m = 16 * mt + lc;
      kfrag[mt] = *(const bf16x8*)(smem + K_B + m * 512 + (((4 * h + lq2) ^ (m & 31)) & 31) * 16);
    }
    const float scale = 0.17677669529663687f;
#pragma unroll
    for (int qt = 0; qt < 4; ++qt) {
      const int n = 16 * qt + lc;
      const bf16x8 qfrag = *(const bf16x8*)(smem + Q_B + n * 512 + (((4 * h + lq2) ^ (n & 31)) & 31) * 16);
      f32x4 sc[4];
#pragma unroll
      for (int mt = 0; mt < 4; ++mt)
        sc[mt] = __builtin_amdgcn_mfma_f32_16x16x32_bf16(kfrag[mt], qfrag, zero4, 0, 0, 0);
      // scale + relative-position bias (s^T[m][n] = attn[n][m])
      const int* relrow = rel + n * 64;
      float sv[4][4];
#pragma unroll
      for (int mt = 0; mt < 4; ++mt)
#pragma unroll
        for (int r = 0; r < 4; ++r) {
          const int m = 16 * mt + 4 * lq2 + r;
          sv[mt][r] = sc[mt][r] * scale + bt[relrow[m] * 8 + h];
        }
      // softmax over m: 16 in-reg + 2 shuffles
      float mx = sv[0][0];
#pragma unroll
      for (int mt = 0; mt < 4; ++mt)
#pragma unroll
        for (int r = 0; r < 4; ++r) mx = fmaxf(mx, sv[mt][r]);
      mx = fmaxf(mx, __shfl_xor(mx, 16));
      mx = fmaxf(mx, __shfl_xor(mx, 32));
      float sum = 0.f;
#pragma unroll
      for (int mt = 0; mt < 4; ++mt)
#pragma unroll
        for (int r = 0; r < 4; ++r) {
          sv[mt][r] = __expf(sv[mt][r] - mx);
          sum += sv[mt][r];
        }
      sum += __shfl_xor(sum, 16);
      sum += __shfl_xor(sum, 32);
      const float rinv = __builtin_amdgcn_rcpf(sum);
      // write unnormalized P (b64) into per-wave P-buf
#pragma unroll
      for (int mt = 0; mt < 4; ++mt) {
        const int m0 = 16 * mt + 4 * lq2;
        uint2 u; u.x = pk2(sv[mt][0], sv[mt][1]); u.y = pk2(sv[mt][2], sv[mt][3]);
        *(uint2*)(smem + SLICE_B + wv * 2048 + lc * 128 +
                  (((m0 >> 3) ^ (lc & 7)) & 7) * 16 + (lq2 & 1) * 8) = u;
      }
      // PV (transposed): o^T[c][n]
      f32x4 o[2] = {zero4, zero4};
#pragma unroll
      for (int kk = 0; kk < 2; ++kk) {
        const bf16x8 pf = *(const bf16x8*)(smem + SLICE_B + wv * 2048 + lc * 128 +
                                           (((4 * kk + lq2) ^ (lc & 7)) & 7) * 16);
#pragma unroll
        for (int ct = 0; ct < 2; ++ct)
          o[ct] = __builtin_amdgcn_mfma_f32_16x16x32_bf16(vfrag[ct][kk], pf, o[ct], 0, 0, 0);
      }
      // normalize + write attn-out^T as [n][c] (b64) into K region
#pragma unroll
      for (int ct = 0; ct < 2; ++ct) {
        const int c0 = 32 * h + 16 * ct + 4 * lq2;
        const float v0 = o[ct][0] * rinv, v1 = o[ct][1] * rinv;
        const float v2 = o[ct][2] * rinv, v3 = o[ct][3] * rinv;
        uint2 u; u.x = pk2(v0, v1); u.y = pk2(v2, v3);
        *(uint2*)(smem + K_B + n * 512 + (((c0 >> 3) ^ (n & 31)) & 31) * 16 + (lq2 & 1) * 8) = u;
      }
    }
  }
  __syncthreads();

  // =============== projection GEMM + bias -> global f32 ===============
  {
    f32x4 pacc[4][2];
#pragma unroll
    for (int i = 0; i < 4; ++i)
#pragma unroll
      for (int t = 0; t < 2; ++t) pacc[i][t] = zero4;
#pragma unroll
    for (int kk = 0; kk < 8; ++kk) {
      bf16x8 afr[4];
#pragma unroll
      for (int i = 0; i < 4; ++i) {
        const int n = 16 * i + lc;
        afr[i] = *(const bf16x8*)(smem + K_B + n * 512 + (((4 * kk + lq2) ^ (n & 31)) & 31) * 16);
      }
      bf16x8 bb[2];
#pragma unroll
      for (int t = 0; t < 2; ++t) {
        const int co = 16 * (2 * wv + t) + lc;
        const float4 wa = *(const float4*)(pjw + co * 256 + 32 * kk + 8 * lq2);
        const float4 wb = *(const float4*)(pjw + co * 256 + 32 * kk + 8 * lq2 + 4);
        bb[t] = pack8(wa, wb);
      }
#pragma unroll
      for (int i = 0; i < 4; ++i)
#pragma unroll
        for (int t = 0; t < 2; ++t)
          pacc[i][t] = __builtin_amdgcn_mfma_f32_16x16x32_bf16(afr[i], bb[t], pacc[i][t], 0, 0, 0);
    }
    float* og = outg + (size_t)b * 16384;
#pragma unroll
    for (int t = 0; t < 2; ++t) {
      const int co = 16 * (2 * wv + t) + lc;
      const float pbv = pjb[co];
#pragma unroll
      for (int i = 0; i < 4; ++i)
#pragma unroll
        for (int r = 0; r < 4; ++r)
          og[(16 * i + 4 * lq2 + r) * 256 + co] = pacc[i][t][r] + pbv;
    }
  }
}

extern "C" void kernel_launch(void* const* d_in, const int* in_sizes, int n_in,
                              void* d_out, int out_size, void* d_ws, size_t ws_size,
                              hipStream_t stream) {
  (void)in_sizes; (void)n_in; (void)d_ws; (void)ws_size; (void)out_size;
  const float* x    = (const float*)d_in[0];
  const float* qdww = (const float*)d_in[1];
  const float* qdwb = (const float*)d_in[2];
  const float* qpww = (const float*)d_in[3];
  const float* qpwb = (const float*)d_in[4];
  const float* kdww = (const float*)d_in[5];
  const float* kdwb = (const float*)d_in[6];
  const float* kpww = (const float*)d_in[7];
  const float* kpwb = (const float*)d_in[8];
  const float* vdww = (const float*)d_in[9];
  const float* vdwb = (const float*)d_in[10];
  const float* vpww = (const float*)d_in[11];
  const float* vpwb = (const float*)d_in[12];
  const float* bt   = (const float*)d_in[13];
  const float* pjw  = (const float*)d_in[14];
  const float* pjb  = (const float*)d_in[15];
  const int* rel    = (const int*)d_in[16];
  float* out        = (float*)d_out;

  hipLaunchKernelGGL(winattn_kernel, dim3(4096), dim3(512), 0, stream,
                     x, qdww, qdwb, qpww, qpwb, kdww, kdwb, kpww, kpwb,
                     vdww, vdwb, vpww, vpwb, bt, pjw, pjb, rel, out);
}